// Round 3
// baseline (508.823 us; speedup 1.0000x reference)
//
#include <hip/hip_runtime.h>

#define BB   64
#define S    2048
#define HH   128
#define KCH  682          // S/3 chunks
#define TT   78           // output t per block (26 chunks)
#define NTB  27           // ceil(2046/78): covers t up to 2105, tail guarded
#define STRIDE 84         // LDS row stride (floats); 84*4 B % 16 == 0 -> b128-aligned rows
#define EPS  1e-5f

// ---------------- setup: transpose weights [c][ci][tap] -> [ci*3+tap][c] ----------------
__global__ void transpose_w(const float* __restrict__ w1, const float* __restrict__ w2,
                            const float* __restrict__ pw,
                            float* __restrict__ o1, float* __restrict__ o2,
                            float* __restrict__ o3) {
    int gid = blockIdx.x * 256 + threadIdx.x;      // 3*49152 total
    int a = gid / 49152;
    int j = gid - a * 49152;
    const float* src = (a == 0) ? w1 : (a == 1) ? w2 : pw;
    float*       dst = (a == 0) ? o1 : (a == 1) ? o2 : o3;
    int m = j >> 7, c = j & 127;                   // j = m*128 + c
    dst[j] = src[c * 384 + m];                     // coalesced write, strided read (tiny)
}

// seq_lens may arrive as int64 (reference dtype) or int32 (harness doc). Detect:
// under int64 little-endian, int32 slots 1,3,...,63 are high words == 0 (values < 2048).
// Under int32, odd slots are random in [0,2048): all-zero has prob ~2^-352.
__device__ __forceinline__ int read_seqlen(const int* seq, int b) {
    bool is64 = true;
    for (int i = 1; i < 64; i += 2) { if (seq[i] != 0) { is64 = false; break; } }
    return is64 ? seq[2 * b] : seq[b];
}

__device__ __forceinline__ void stage_w(float* __restrict__ wtS,
                                        const float* __restrict__ wtG,   // transposed [m][c]
                                        const float* __restrict__ wraw,  // raw [c][m]
                                        int use_t, int cc, int tid) {
    if (use_t) {
        #pragma unroll
        for (int i4 = tid; i4 < 1536; i4 += 256)
            *(float4*)&wtS[i4 * 4] = *(const float4*)&wtG[cc * 384 + i4 * 4];
    } else {
        for (int i = tid; i < 6144; i += 256)
            wtS[i] = wraw[(i & 127) * 384 + cc * 3 + (i >> 7)];
    }
}

// GEMM over K=384 (128 ci x 3 taps): acc[i][q] += h[tbase+i+tap] * W[ci][tap][c0+q]
__device__ __forceinline__ void conv_gemm(float (&acc)[10][4],
                                          const float* __restrict__ wtG,
                                          const float* __restrict__ wraw,
                                          int use_t,
                                          const float* __restrict__ hAp,
                                          float* __restrict__ wtS,
                                          int tid, int c0, int tbase) {
    #pragma unroll
    for (int i = 0; i < 10; ++i)
        #pragma unroll
        for (int q = 0; q < 4; ++q) acc[i][q] = 0.f;

    for (int cc = 0; cc < HH; cc += 16) {
        __syncthreads();
        stage_w(wtS, wtG, wraw, use_t, cc, tid);
        __syncthreads();
        for (int ci = 0; ci < 16; ++ci) {
            float hr[12];
            #pragma unroll
            for (int j = 0; j < 12; ++j) hr[j] = hAp[(cc + ci) * STRIDE + tbase + j];
            #pragma unroll
            for (int tap = 0; tap < 3; ++tap) {
                const float4 w = *(const float4*)&wtS[((ci * 3 + tap) << 7) + c0];
                #pragma unroll
                for (int i = 0; i < 10; ++i) {
                    const float h = hr[i + tap];
                    acc[i][0] = fmaf(h, w.x, acc[i][0]);
                    acc[i][1] = fmaf(h, w.y, acc[i][1]);
                    acc[i][2] = fmaf(h, w.z, acc[i][2]);
                    acc[i][3] = fmaf(h, w.w, acc[i][3]);
                }
            }
        }
    }
}

__global__ __launch_bounds__(256, 2)
void fused_pd(const float* __restrict__ x, const int* __restrict__ seq,
              const float* __restrict__ w0, const float* __restrict__ b0,
              const float* __restrict__ w1raw, const float* __restrict__ b1,
              const float* __restrict__ w2raw, const float* __restrict__ b2,
              const float* __restrict__ bng, const float* __restrict__ bnb,
              const float* __restrict__ bnm, const float* __restrict__ bnv,
              const float* __restrict__ pwraw, const float* __restrict__ pb,
              const float* __restrict__ fcw, const float* __restrict__ fcb,
              const float* __restrict__ wt1, const float* __restrict__ wt2,
              const float* __restrict__ pwt, int use_t,
              float* __restrict__ out) {
    __shared__ __align__(16) float hA[HH * STRIDE];   // 43008 B: h1T -> h2T -> h3T
    __shared__ __align__(16) float wtS[6144];         // 24576 B: weight chunk [16ci][3tap][128c]
    __shared__ __align__(16) float xs[TT + 8];
    __shared__ int nch_s;

    const int tid = threadIdx.x;
    const int b  = blockIdx.x / NTB;
    const int jt = blockIdx.x - b * NTB;
    const int t0 = jt * TT;

    // ---- phase 0: stage x tile (halo 3 each side) ----
    for (int j = tid; j < TT + 6; j += 256) {         // 84 values: t0-3 .. t0+80
        const int t = t0 - 3 + j;
        xs[j] = (t >= 0 && t < S) ? x[b * S + t] : 0.f;
    }
    // n_chunks = seq_len // 3  (the round-2 bug: compared kG to raw seq_len)
    if (tid == 0) nch_s = read_seqlen(seq, b) / 3;

    // conv0 per-thread constants (c fixed = tid&127 for phase-1 mapping)
    const int cch = tid & 127;
    const float w0a = w0[cch * 3 + 0], w0b = w0[cch * 3 + 1], w0c = w0[cch * 3 + 2];
    const float bb0 = b0[cch];
    const float a0 = bng[cch] * rsqrtf(bnv[cch] + EPS);
    const float d0 = bnb[cch] - bnm[cch] * a0;
    __syncthreads();

    // ---- phase 1: conv0+bn0 -> h1T[c][tt1], tt1 in [0,82), t = t0-2+tt1 ----
    for (int i = tid; i < (TT + 4) * HH; i += 256) {
        const int ttl = i >> 7;                       // channel of this slot == cch
        const int t = t0 - 2 + ttl;
        float v = 0.f;
        if (t >= 0 && t < S) {
            // x[t-1],x[t],x[t+1] = xs[ttl], xs[ttl+1], xs[ttl+2]  (xs[j] = x[t0-3+j])
            float sa = fmaf(xs[ttl + 2], w0c, fmaf(xs[ttl + 1], w0b, fmaf(xs[ttl], w0a, bb0)));
            v = fmaf(fmaxf(sa, 0.f), a0, d0);
        }
        hA[cch * STRIDE + ttl] = v;
    }
    // (conv_gemm opens with __syncthreads())

    const int cg = tid & 31, tg = tid >> 5;
    const int c0 = cg * 4;
    const int tbase = tg * 10;
    float acc[10][4];

    // ---- phase 2: conv1 GEMM -> h2T[c][tt2], tt2 in [0,80), t = t0-1+tt2 ----
    conv_gemm(acc, wt1, w1raw, use_t, hA, wtS, tid, c0, tbase);
    {
        const float4 bv = *(const float4*)&b1[c0];
        const float4 g  = *(const float4*)&bng[HH + c0];
        const float4 be = *(const float4*)&bnb[HH + c0];
        const float4 mn = *(const float4*)&bnm[HH + c0];
        const float4 vr = *(const float4*)&bnv[HH + c0];
        float av[4] = { g.x * rsqrtf(vr.x + EPS), g.y * rsqrtf(vr.y + EPS),
                        g.z * rsqrtf(vr.z + EPS), g.w * rsqrtf(vr.w + EPS) };
        float dv[4] = { be.x - mn.x * av[0], be.y - mn.y * av[1],
                        be.z - mn.z * av[2], be.w - mn.w * av[3] };
        float bb[4] = { bv.x, bv.y, bv.z, bv.w };
        __syncthreads();                              // all reads of h1T done
        #pragma unroll
        for (int i = 0; i < 10; ++i) {
            const int tt2 = tbase + i;
            const int t = t0 - 1 + tt2;
            const bool ok = (t >= 0) && (t < S);
            #pragma unroll
            for (int q = 0; q < 4; ++q) {
                float v = 0.f;
                if (ok) v = fmaf(fmaxf(acc[i][q] + bb[q], 0.f), av[q], dv[q]);
                hA[(c0 + q) * STRIDE + tt2] = v;
            }
        }
        __syncthreads();
    }

    // ---- phase 3: conv2 GEMM -> h3T[c][tt3], tt3 in [0,78), t = t0+tt3 ----
    conv_gemm(acc, wt2, w2raw, use_t, hA, wtS, tid, c0, tbase);
    {
        const float4 bv = *(const float4*)&b2[c0];
        const float4 g  = *(const float4*)&bng[2 * HH + c0];
        const float4 be = *(const float4*)&bnb[2 * HH + c0];
        const float4 mn = *(const float4*)&bnm[2 * HH + c0];
        const float4 vr = *(const float4*)&bnv[2 * HH + c0];
        float av[4] = { g.x * rsqrtf(vr.x + EPS), g.y * rsqrtf(vr.y + EPS),
                        g.z * rsqrtf(vr.z + EPS), g.w * rsqrtf(vr.w + EPS) };
        float dv[4] = { be.x - mn.x * av[0], be.y - mn.y * av[1],
                        be.z - mn.z * av[2], be.w - mn.w * av[3] };
        float bb[4] = { bv.x, bv.y, bv.z, bv.w };
        __syncthreads();                              // all reads of h2T done
        #pragma unroll
        for (int i = 0; i < 10; ++i) {
            const int tt3 = tbase + i;
            if (tt3 < TT) {
                const int t = t0 + tt3;
                #pragma unroll
                for (int q = 0; q < 4; ++q) {
                    float vv = 0.f;
                    if (t < S) vv = fmaf(fmaxf(acc[i][q] + bb[q], 0.f), av[q], dv[q]);
                    hA[(c0 + q) * STRIDE + tt3] = vv;
                }
            }
        }
        __syncthreads();
    }

    // ---- phase 4: pre einsum + relu + fc + mask ----
    // z[k][o] = sum_h sum_tap h3[h][3k+tap] * pre_w[o][h][tap]
    const int og = tid & 31, kg = tid >> 5;
    const int oo = og * 4;
    float pacc[4][4];
    #pragma unroll
    for (int j = 0; j < 4; ++j)
        #pragma unroll
        for (int q = 0; q < 4; ++q) pacc[j][q] = 0.f;

    for (int hc = 0; hc < HH; hc += 16) {
        __syncthreads();
        stage_w(wtS, pwt, pwraw, use_t, hc, tid);
        __syncthreads();
        for (int h = 0; h < 16; ++h) {
            #pragma unroll
            for (int tap = 0; tap < 3; ++tap) {
                const float4 w = *(const float4*)&wtS[((h * 3 + tap) << 7) + oo];
                #pragma unroll
                for (int j = 0; j < 4; ++j) {
                    int kl = kg * 4 + j; kl = (kl > 25) ? 25 : kl;   // clamp reads, guard writes
                    const float hv = hA[(hc + h) * STRIDE + 3 * kl + tap];
                    pacc[j][0] = fmaf(hv, w.x, pacc[j][0]);
                    pacc[j][1] = fmaf(hv, w.y, pacc[j][1]);
                    pacc[j][2] = fmaf(hv, w.z, pacc[j][2]);
                    pacc[j][3] = fmaf(hv, w.w, pacc[j][3]);
                }
            }
        }
    }

    const float fcb0 = fcb[0];
    const float4 pbv = *(const float4*)&pb[oo];
    const float4 fwv = *(const float4*)&fcw[oo];
    const int nch = nch_s;
    #pragma unroll
    for (int j = 0; j < 4; ++j) {
        float s = fmaxf(pacc[j][0] + pbv.x, 0.f) * fwv.x
                + fmaxf(pacc[j][1] + pbv.y, 0.f) * fwv.y
                + fmaxf(pacc[j][2] + pbv.z, 0.f) * fwv.z
                + fmaxf(pacc[j][3] + pbv.w, 0.f) * fwv.w;
        #pragma unroll
        for (int m = 1; m < 32; m <<= 1) s += __shfl_xor(s, m, 64);
        // lanes with og==0 in each 32-lane half hold the full sum for their (kg) chunk
        if (og == 0) {
            const int kl = kg * 4 + j;
            const int kG = jt * 26 + kl;
            if (kl < 26 && kG < KCH)
                out[b * KCH + kG] = (kG < nch) ? (s + fcb0) : 0.f;
        }
    }
}

extern "C" void kernel_launch(void* const* d_in, const int* in_sizes, int n_in,
                              void* d_out, int out_size, void* d_ws, size_t ws_size,
                              hipStream_t stream) {
    (void)in_sizes; (void)n_in; (void)out_size;
    const float* x    = (const float*)d_in[0];
    const int*   seq  = (const int*)d_in[1];
    const float* w0   = (const float*)d_in[2];
    const float* b0   = (const float*)d_in[3];
    const float* w1   = (const float*)d_in[4];
    const float* b1   = (const float*)d_in[5];
    const float* w2   = (const float*)d_in[6];
    const float* b2   = (const float*)d_in[7];
    const float* bng  = (const float*)d_in[8];
    const float* bnb  = (const float*)d_in[9];
    const float* bnm  = (const float*)d_in[10];
    const float* bnv  = (const float*)d_in[11];
    const float* pw   = (const float*)d_in[12];
    const float* pb   = (const float*)d_in[13];
    const float* fcw  = (const float*)d_in[14];
    const float* fcb  = (const float*)d_in[15];
    float* out = (float*)d_out;

    const size_t need = (size_t)3 * 49152 * sizeof(float);
    const int use_t = (ws_size >= need) ? 1 : 0;
    float* o1 = (float*)d_ws;
    float* o2 = o1 + 49152;
    float* o3 = o2 + 49152;

    if (use_t)
        transpose_w<<<576, 256, 0, stream>>>(w1, w2, pw, o1, o2, o3);

    fused_pd<<<BB * NTB, 256, 0, stream>>>(x, seq, w0, b0, w1, b1, w2, b2,
                                           bng, bnb, bnm, bnv, pw, pb, fcw, fcb,
                                           o1, o2, o3, use_t, out);
}

// Round 4
// 115.128 us; speedup vs baseline: 4.4196x; 4.4196x over previous
//
#include <hip/hip_runtime.h>

#define BB   64
#define S    2048
#define HH   128
#define KCH  682
#define EPS  1e-5f

// ================= MFMA path =================
#define TT2   96          // output t per block (32 chunks)
#define NTB2  22          // ceil(2046/96)
#define NROWS 114         // hR rows: t in [t0-3, t0+111)

typedef __attribute__((ext_vector_type(8))) short bf16x8;
typedef __attribute__((ext_vector_type(4))) short bf16x4v;
typedef __attribute__((ext_vector_type(4))) float f32x4;

__device__ __forceinline__ unsigned short bf16hi(float v) {
    return (unsigned short)(__float_as_uint(v) >> 16);   // truncation; lo captures residual
}
__device__ __forceinline__ float bf16f(unsigned short h) {
    return __uint_as_float(((unsigned)h) << 16);
}

// Pack W fragments in exact MFMA A-operand order (assumed: row=lane&15, k=(lane>>4)*8+j;
// any k-permutation error cancels against the B-read which uses the same mapping).
// Layout: frag_idx = ((mat*12+kb)*8+mc)*2+pl ; 512 ushort per frag (64 lanes x 8).
__global__ void pack_w_frags(const float* __restrict__ w1, const float* __restrict__ w2,
                             const float* __restrict__ pw, unsigned short* __restrict__ wpk) {
    int u = blockIdx.x * 256 + threadIdx.x;     // 18432 units
    if (u >= 18432) return;
    int lane = u & 63, mc = (u >> 6) & 7, kb = (u >> 9) % 12, mat = u / 6144;
    const float* src = (mat == 0) ? w1 : (mat == 1) ? w2 : pw;
    int c = mc * 16 + (lane & 15);
    int kbase = kb * 32 + ((lane >> 4) << 3);
    bf16x8 hv, lv;
    #pragma unroll
    for (int j = 0; j < 8; ++j) {
        int k = kbase + j, tap = k >> 7, ci = k & 127;   // K = tap*128 + ci
        float v = src[c * 384 + ci * 3 + tap];
        unsigned short h = bf16hi(v);
        float r = v - bf16f(h);
        hv[j] = (short)h;
        lv[j] = (short)bf16hi(r);
    }
    int fb = ((mat * 12 + kb) * 8 + mc) * 2;
    *(bf16x8*)(wpk + (size_t)(fb + 0) * 512 + lane * 8) = hv;
    *(bf16x8*)(wpk + (size_t)(fb + 1) * 512 + lane * 8) = lv;
}

// seq_lens may arrive as int64 (reference dtype) or int32. Detect (odd slots all-zero => int64).
__device__ __forceinline__ int read_seqlen(const int* seq, int b) {
    bool is64 = true;
    for (int i = 1; i < 64; i += 2) { if (seq[i] != 0) { is64 = false; break; } }
    return is64 ? seq[2 * b] : seq[b];
}

// swizzled byte address into a [NROWS][128] ushort plane: row rr, 16B-chunk index
__device__ __forceinline__ int haddr(int rr, int chunk) {
    return (rr << 8) | ((chunk ^ (rr & 15)) << 4);
}

__device__ __forceinline__ void conv_mfma_k(
        f32x4 (&acc)[2][7], const unsigned short* __restrict__ wpk, int mat,
        const unsigned short* __restrict__ hHi, const unsigned short* __restrict__ hLo,
        int wv, int lane) {
    #pragma unroll
    for (int m = 0; m < 2; ++m)
        #pragma unroll
        for (int n = 0; n < 7; ++n) acc[m][n] = (f32x4){0.f, 0.f, 0.f, 0.f};

    const bf16x8* wp = (const bf16x8*)wpk;
    for (int kb = 0; kb < 12; ++kb) {
        const int fb = ((mat * 12 + kb) * 8 + wv * 2) * 2;   // this wave's 2 c-tiles
        bf16x8 a0h = wp[(size_t)(fb + 0) * 64 + lane];
        bf16x8 a0l = wp[(size_t)(fb + 1) * 64 + lane];
        bf16x8 a1h = wp[(size_t)(fb + 2) * 64 + lane];
        bf16x8 a1l = wp[(size_t)(fb + 3) * 64 + lane];
        const int tap = kb >> 2;
        const int chunk = (kb & 3) * 4 + (lane >> 4);
        const int rr0 = (lane & 15) + tap;
        #pragma unroll
        for (int nt = 0; nt < 7; ++nt) {
            const int rr = rr0 + nt * 16;
            const int ad = haddr(rr, chunk);
            bf16x8 bh = *(const bf16x8*)((const char*)hHi + ad);
            bf16x8 bl = *(const bf16x8*)((const char*)hLo + ad);
            acc[0][nt] = __builtin_amdgcn_mfma_f32_16x16x32_bf16(a0h, bh, acc[0][nt], 0, 0, 0);
            acc[0][nt] = __builtin_amdgcn_mfma_f32_16x16x32_bf16(a0l, bh, acc[0][nt], 0, 0, 0);
            acc[0][nt] = __builtin_amdgcn_mfma_f32_16x16x32_bf16(a0h, bl, acc[0][nt], 0, 0, 0);
            acc[1][nt] = __builtin_amdgcn_mfma_f32_16x16x32_bf16(a1h, bh, acc[1][nt], 0, 0, 0);
            acc[1][nt] = __builtin_amdgcn_mfma_f32_16x16x32_bf16(a1l, bh, acc[1][nt], 0, 0, 0);
            acc[1][nt] = __builtin_amdgcn_mfma_f32_16x16x32_bf16(a1h, bl, acc[1][nt], 0, 0, 0);
        }
    }
}

// BN+relu epilogue: write h (bf16 hi/lo) rows rr = 1 + nt*16 + (lane&15)
__device__ __forceinline__ void conv_epilogue(
        f32x4 (&acc)[2][7], const float* __restrict__ bias,
        const float* __restrict__ bng, const float* __restrict__ bnb,
        const float* __restrict__ bnm, const float* __restrict__ bnv, int layer,
        unsigned short* __restrict__ hHi, unsigned short* __restrict__ hLo,
        int wv, int lane, int t0) {
    #pragma unroll
    for (int m = 0; m < 2; ++m) {
        const int c0 = (wv * 2 + m) * 16 + (lane >> 4) * 4;
        const float4 bv = *(const float4*)&bias[c0];
        const float4 g  = *(const float4*)&bng[layer * 128 + c0];
        const float4 be = *(const float4*)&bnb[layer * 128 + c0];
        const float4 mn = *(const float4*)&bnm[layer * 128 + c0];
        const float4 vr = *(const float4*)&bnv[layer * 128 + c0];
        const float av[4] = { g.x * rsqrtf(vr.x + EPS), g.y * rsqrtf(vr.y + EPS),
                              g.z * rsqrtf(vr.z + EPS), g.w * rsqrtf(vr.w + EPS) };
        const float dv[4] = { be.x - mn.x * av[0], be.y - mn.y * av[1],
                              be.z - mn.z * av[2], be.w - mn.w * av[3] };
        const float bb[4] = { bv.x, bv.y, bv.z, bv.w };
        const int byte = c0 * 2, chunk = byte >> 4, off = byte & 15;
        #pragma unroll
        for (int nt = 0; nt < 7; ++nt) {
            const int tt = nt * 16 + (lane & 15);
            const int t = t0 - 2 + tt;
            const int rr = tt + 1;
            const bool ok = (t >= 0) && (t < S);
            bf16x4v h4, l4;
            #pragma unroll
            for (int r = 0; r < 4; ++r) {
                float v = 0.f;
                if (ok) v = fmaf(fmaxf(acc[m][nt][r] + bb[r], 0.f), av[r], dv[r]);
                unsigned short h = bf16hi(v);
                float res = v - bf16f(h);
                h4[r] = (short)h;
                l4[r] = (short)bf16hi(res);
            }
            const int ad = haddr(rr, chunk) | off;
            *(bf16x4v*)((char*)hHi + ad) = h4;
            *(bf16x4v*)((char*)hLo + ad) = l4;
        }
    }
}

__global__ __launch_bounds__(256, 2)
void fused_mfma(const float* __restrict__ x, const int* __restrict__ seq,
                const float* __restrict__ w0, const float* __restrict__ b0,
                const float* __restrict__ b1, const float* __restrict__ b2,
                const float* __restrict__ bng, const float* __restrict__ bnb,
                const float* __restrict__ bnm, const float* __restrict__ bnv,
                const float* __restrict__ pb, const float* __restrict__ fcw,
                const float* __restrict__ fcb, const unsigned short* __restrict__ wpk,
                float* __restrict__ out) {
    __shared__ __align__(16) unsigned short hHi[NROWS * 128];
    __shared__ __align__(16) unsigned short hLo[NROWS * 128];
    __shared__ __align__(16) float xs[120];
    __shared__ float p0[6 * 128];
    __shared__ float zred[4][32];
    __shared__ int nch_s;

    const int tid = threadIdx.x;
    const int lane = tid & 63, wv = tid >> 6;
    const int b  = blockIdx.x / NTB2;
    const int jt = blockIdx.x - b * NTB2;
    const int t0 = jt * TT2;

    // ---- stage x (halo 4/..) + conv0/bn0 per-channel constants ----
    if (tid < 116) {
        const int t = t0 - 4 + tid;
        xs[tid] = (t >= 0 && t < S) ? x[b * S + t] : 0.f;
    }
    if (tid < 128) {
        const int c = tid;
        p0[c]         = w0[c * 3 + 0];
        p0[128 + c]   = w0[c * 3 + 1];
        p0[2*128 + c] = w0[c * 3 + 2];
        p0[3*128 + c] = b0[c];
        const float a0 = bng[c] * rsqrtf(bnv[c] + EPS);
        p0[4*128 + c] = a0;
        p0[5*128 + c] = bnb[c] - bnm[c] * a0;
    }
    if (tid == 0) nch_s = read_seqlen(seq, b) / 3;
    __syncthreads();

    // ---- conv0 + bn0 -> h1 rows rr=0..113 (t = t0-3+rr), bf16 hi/lo ----
    for (int it = 0; it < 8; ++it) {
        const int u = tid + it * 256;              // 1824 units = 114 rows x 16 octets
        if (u < NROWS * 16) {
            const int rr = u >> 4, oct = u & 15, ci0 = oct * 8;
            const int t = t0 - 3 + rr;
            const bool ok = (t >= 0) && (t < S);
            const float xm = xs[rr], xc = xs[rr + 1], xp = xs[rr + 2];
            bf16x8 hv, lv;
            #pragma unroll
            for (int q = 0; q < 8; ++q) {
                const int c = ci0 + q;
                float v = 0.f;
                if (ok) {
                    float sa = fmaf(xp, p0[2*128 + c],
                               fmaf(xc, p0[128 + c],
                               fmaf(xm, p0[c], p0[3*128 + c])));
                    v = fmaf(fmaxf(sa, 0.f), p0[4*128 + c], p0[5*128 + c]);
                }
                unsigned short h = bf16hi(v);
                float res = v - bf16f(h);
                hv[q] = (short)h;
                lv[q] = (short)bf16hi(res);
            }
            const int ad = haddr(rr, oct);
            *(bf16x8*)((char*)hHi + ad) = hv;
            *(bf16x8*)((char*)hLo + ad) = lv;
        }
    }
    __syncthreads();

    f32x4 acc[2][7];

    // ---- conv1 ----
    conv_mfma_k(acc, wpk, 0, hHi, hLo, wv, lane);
    __syncthreads();                                // all h1 reads done
    conv_epilogue(acc, b1, bng, bnb, bnm, bnv, 1, hHi, hLo, wv, lane, t0);
    __syncthreads();

    // ---- conv2 ----
    conv_mfma_k(acc, wpk, 1, hHi, hLo, wv, lane);
    __syncthreads();
    conv_epilogue(acc, b2, bng, bnb, bnm, bnv, 2, hHi, hLo, wv, lane, t0);
    __syncthreads();

    // ---- pre einsum: z[k][o], m=o (A=pre_w frags), n=k-chunks ----
    f32x4 pacc[2][2];
    #pragma unroll
    for (int m = 0; m < 2; ++m)
        #pragma unroll
        for (int n = 0; n < 2; ++n) pacc[m][n] = (f32x4){0.f, 0.f, 0.f, 0.f};
    {
        const bf16x8* wp = (const bf16x8*)wpk;
        for (int kb = 0; kb < 12; ++kb) {
            const int fb = ((2 * 12 + kb) * 8 + wv * 2) * 2;
            bf16x8 a0h = wp[(size_t)(fb + 0) * 64 + lane];
            bf16x8 a0l = wp[(size_t)(fb + 1) * 64 + lane];
            bf16x8 a1h = wp[(size_t)(fb + 2) * 64 + lane];
            bf16x8 a1l = wp[(size_t)(fb + 3) * 64 + lane];
            const int tap = kb >> 2;
            const int chunk = (kb & 3) * 4 + (lane >> 4);
            #pragma unroll
            for (int kt = 0; kt < 2; ++kt) {
                const int klocal = kt * 16 + (lane & 15);
                const int rr = 3 + 3 * klocal + tap;          // h3 row for t = t0+3k+tap
                const int ad = haddr(rr, chunk);
                bf16x8 bh = *(const bf16x8*)((const char*)hHi + ad);
                bf16x8 bl = *(const bf16x8*)((const char*)hLo + ad);
                pacc[0][kt] = __builtin_amdgcn_mfma_f32_16x16x32_bf16(a0h, bh, pacc[0][kt], 0, 0, 0);
                pacc[0][kt] = __builtin_amdgcn_mfma_f32_16x16x32_bf16(a0l, bh, pacc[0][kt], 0, 0, 0);
                pacc[0][kt] = __builtin_amdgcn_mfma_f32_16x16x32_bf16(a0h, bl, pacc[0][kt], 0, 0, 0);
                pacc[1][kt] = __builtin_amdgcn_mfma_f32_16x16x32_bf16(a1h, bh, pacc[1][kt], 0, 0, 0);
                pacc[1][kt] = __builtin_amdgcn_mfma_f32_16x16x32_bf16(a1l, bh, pacc[1][kt], 0, 0, 0);
                pacc[1][kt] = __builtin_amdgcn_mfma_f32_16x16x32_bf16(a1h, bl, pacc[1][kt], 0, 0, 0);
            }
        }
    }

    // ---- relu(z+pb)*fcw, reduce over o ----
    float s0 = 0.f, s1 = 0.f;
    #pragma unroll
    for (int m = 0; m < 2; ++m) {
        const int o0 = (wv * 2 + m) * 16 + (lane >> 4) * 4;
        const float4 pbv = *(const float4*)&pb[o0];
        const float4 fwv = *(const float4*)&fcw[o0];
        const float pbb[4] = { pbv.x, pbv.y, pbv.z, pbv.w };
        const float fww[4] = { fwv.x, fwv.y, fwv.z, fwv.w };
        #pragma unroll
        for (int r = 0; r < 4; ++r) {
            s0 += fmaxf(pacc[m][0][r] + pbb[r], 0.f) * fww[r];
            s1 += fmaxf(pacc[m][1][r] + pbb[r], 0.f) * fww[r];
        }
    }
    s0 += __shfl_xor(s0, 16); s0 += __shfl_xor(s0, 32);
    s1 += __shfl_xor(s1, 16); s1 += __shfl_xor(s1, 32);
    if (lane < 32) zred[wv][lane] = (lane < 16) ? s0 : s1;   // k = lane
    __syncthreads();
    if (tid < 32) {
        const float zz = zred[0][tid] + zred[1][tid] + zred[2][tid] + zred[3][tid];
        const int kG = jt * 32 + tid;
        if (kG < KCH)
            out[b * KCH + kG] = (kG < nch_s) ? (zz + fcb[0]) : 0.f;
    }
}

// ================= fp32 fallback (round-3 verified) =================
#define TT   78
#define NTB  27
#define STRIDE 84

__device__ __forceinline__ void stage_w_fb(float* __restrict__ wtS,
                                           const float* __restrict__ wraw, int cc, int tid) {
    for (int i = tid; i < 6144; i += 256)
        wtS[i] = wraw[(i & 127) * 384 + cc * 3 + (i >> 7)];
}

__device__ __forceinline__ void conv_gemm_fb(float (&acc)[10][4],
                                             const float* __restrict__ wraw,
                                             const float* __restrict__ hAp,
                                             float* __restrict__ wtS,
                                             int tid, int c0, int tbase) {
    #pragma unroll
    for (int i = 0; i < 10; ++i)
        #pragma unroll
        for (int q = 0; q < 4; ++q) acc[i][q] = 0.f;
    for (int cc = 0; cc < HH; cc += 16) {
        __syncthreads();
        stage_w_fb(wtS, wraw, cc, tid);
        __syncthreads();
        for (int ci = 0; ci < 16; ++ci) {
            float hr[12];
            #pragma unroll
            for (int j = 0; j < 12; ++j) hr[j] = hAp[(cc + ci) * STRIDE + tbase + j];
            #pragma unroll
            for (int tap = 0; tap < 3; ++tap) {
                const float4 w = *(const float4*)&wtS[((ci * 3 + tap) << 7) + c0];
                #pragma unroll
                for (int i = 0; i < 10; ++i) {
                    const float h = hr[i + tap];
                    acc[i][0] = fmaf(h, w.x, acc[i][0]);
                    acc[i][1] = fmaf(h, w.y, acc[i][1]);
                    acc[i][2] = fmaf(h, w.z, acc[i][2]);
                    acc[i][3] = fmaf(h, w.w, acc[i][3]);
                }
            }
        }
    }
}

__global__ __launch_bounds__(256, 2)
void fused_pd(const float* __restrict__ x, const int* __restrict__ seq,
              const float* __restrict__ w0, const float* __restrict__ b0,
              const float* __restrict__ w1raw, const float* __restrict__ b1,
              const float* __restrict__ w2raw, const float* __restrict__ b2,
              const float* __restrict__ bng, const float* __restrict__ bnb,
              const float* __restrict__ bnm, const float* __restrict__ bnv,
              const float* __restrict__ pwraw, const float* __restrict__ pb,
              const float* __restrict__ fcw, const float* __restrict__ fcb,
              float* __restrict__ out) {
    __shared__ __align__(16) float hA[HH * STRIDE];
    __shared__ __align__(16) float wtS[6144];
    __shared__ __align__(16) float xsf[TT + 8];
    __shared__ int nch_s;

    const int tid = threadIdx.x;
    const int b  = blockIdx.x / NTB;
    const int jt = blockIdx.x - b * NTB;
    const int t0 = jt * TT;

    for (int j = tid; j < TT + 6; j += 256) {
        const int t = t0 - 3 + j;
        xsf[j] = (t >= 0 && t < S) ? x[b * S + t] : 0.f;
    }
    if (tid == 0) nch_s = read_seqlen(seq, b) / 3;

    const int cch = tid & 127;
    const float w0a = w0[cch * 3 + 0], w0b = w0[cch * 3 + 1], w0c = w0[cch * 3 + 2];
    const float bb0 = b0[cch];
    const float a0 = bng[cch] * rsqrtf(bnv[cch] + EPS);
    const float d0 = bnb[cch] - bnm[cch] * a0;
    __syncthreads();

    for (int i = tid; i < (TT + 4) * HH; i += 256) {
        const int ttl = i >> 7;
        const int t = t0 - 2 + ttl;
        float v = 0.f;
        if (t >= 0 && t < S) {
            float sa = fmaf(xsf[ttl + 2], w0c, fmaf(xsf[ttl + 1], w0b, fmaf(xsf[ttl], w0a, bb0)));
            v = fmaf(fmaxf(sa, 0.f), a0, d0);
        }
        hA[cch * STRIDE + ttl] = v;
    }

    const int cg = tid & 31, tg = tid >> 5;
    const int c0 = cg * 4;
    const int tbase = tg * 10;
    float acc[10][4];

    conv_gemm_fb(acc, w1raw, hA, wtS, tid, c0, tbase);
    {
        const float4 bv = *(const float4*)&b1[c0];
        const float4 g  = *(const float4*)&bng[HH + c0];
        const float4 be = *(const float4*)&bnb[HH + c0];
        const float4 mn = *(const float4*)&bnm[HH + c0];
        const float4 vr = *(const float4*)&bnv[HH + c0];
        float av[4] = { g.x * rsqrtf(vr.x + EPS), g.y * rsqrtf(vr.y + EPS),
                        g.z * rsqrtf(vr.z + EPS), g.w * rsqrtf(vr.w + EPS) };
        float dv[4] = { be.x - mn.x * av[0], be.y - mn.y * av[1],
                        be.z - mn.z * av[2], be.w - mn.w * av[3] };
        float bb[4] = { bv.x, bv.y, bv.z, bv.w };
        __syncthreads();
        #pragma unroll
        for (int i = 0; i < 10; ++i) {
            const int tt2 = tbase + i;
            const int t = t0 - 1 + tt2;
            const bool ok = (t >= 0) && (t < S);
            #pragma unroll
            for (int q = 0; q < 4; ++q) {
                float v = 0.f;
                if (ok) v = fmaf(fmaxf(acc[i][q] + bb[q], 0.f), av[q], dv[q]);
                hA[(c0 + q) * STRIDE + tt2] = v;
            }
        }
        __syncthreads();
    }

    conv_gemm_fb(acc, w2raw, hA, wtS, tid, c0, tbase);
    {
        const float4 bv = *(const float4*)&b2[c0];
        const float4 g  = *(const float4*)&bng[2 * HH + c0];
        const float4 be = *(const float4*)&bnb[2 * HH + c0];
        const float4 mn = *(const float4*)&bnm[2 * HH + c0];
        const float4 vr = *(const float4*)&bnv[2 * HH + c0];
        float av[4] = { g.x * rsqrtf(vr.x + EPS), g.y * rsqrtf(vr.y + EPS),
                        g.z * rsqrtf(vr.z + EPS), g.w * rsqrtf(vr.w + EPS) };
        float dv[4] = { be.x - mn.x * av[0], be.y - mn.y * av[1],
                        be.z - mn.z * av[2], be.w - mn.w * av[3] };
        float bb[4] = { bv.x, bv.y, bv.z, bv.w };
        __syncthreads();
        #pragma unroll
        for (int i = 0; i < 10; ++i) {
            const int tt3 = tbase + i;
            if (tt3 < TT) {
                const int t = t0 + tt3;
                #pragma unroll
                for (int q = 0; q < 4; ++q) {
                    float vv = 0.f;
                    if (t < S) vv = fmaf(fmaxf(acc[i][q] + bb[q], 0.f), av[q], dv[q]);
                    hA[(c0 + q) * STRIDE + tt3] = vv;
                }
            }
        }
        __syncthreads();
    }

    const int og = tid & 31, kg = tid >> 5;
    const int oo = og * 4;
    float pacc[4][4];
    #pragma unroll
    for (int j = 0; j < 4; ++j)
        #pragma unroll
        for (int q = 0; q < 4; ++q) pacc[j][q] = 0.f;

    for (int hc = 0; hc < HH; hc += 16) {
        __syncthreads();
        stage_w_fb(wtS, pwraw, hc, tid);
        __syncthreads();
        for (int h = 0; h < 16; ++h) {
            #pragma unroll
            for (int tap = 0; tap < 3; ++tap) {
                const float4 w = *(const float4*)&wtS[((h * 3 + tap) << 7) + oo];
                #pragma unroll
                for (int j = 0; j < 4; ++j) {
                    int kl = kg * 4 + j; kl = (kl > 25) ? 25 : kl;
                    const float hv = hA[(hc + h) * STRIDE + 3 * kl + tap];
                    pacc[j][0] = fmaf(hv, w.x, pacc[j][0]);
                    pacc[j][1] = fmaf(hv, w.y, pacc[j][1]);
                    pacc[j][2] = fmaf(hv, w.z, pacc[j][2]);
                    pacc[j][3] = fmaf(hv, w.w, pacc[j][3]);
                }
            }
        }
    }

    const float fcb0 = fcb[0];
    const float4 pbv = *(const float4*)&pb[oo];
    const float4 fwv = *(const float4*)&fcw[oo];
    const int nch = nch_s;
    #pragma unroll
    for (int j = 0; j < 4; ++j) {
        float s = fmaxf(pacc[j][0] + pbv.x, 0.f) * fwv.x
                + fmaxf(pacc[j][1] + pbv.y, 0.f) * fwv.y
                + fmaxf(pacc[j][2] + pbv.z, 0.f) * fwv.z
                + fmaxf(pacc[j][3] + pbv.w, 0.f) * fwv.w;
        #pragma unroll
        for (int m = 1; m < 32; m <<= 1) s += __shfl_xor(s, m, 64);
        if (og == 0) {
            const int kl = kg * 4 + j;
            const int kG = jt * 26 + kl;
            if (kl < 26 && kG < KCH)
                out[b * KCH + kG] = (kG < nch) ? (s + fcb0) : 0.f;
        }
    }
}

extern "C" void kernel_launch(void* const* d_in, const int* in_sizes, int n_in,
                              void* d_out, int out_size, void* d_ws, size_t ws_size,
                              hipStream_t stream) {
    (void)in_sizes; (void)n_in; (void)out_size;
    const float* x    = (const float*)d_in[0];
    const int*   seq  = (const int*)d_in[1];
    const float* w0   = (const float*)d_in[2];
    const float* b0   = (const float*)d_in[3];
    const float* w1   = (const float*)d_in[4];
    const float* b1   = (const float*)d_in[5];
    const float* w2   = (const float*)d_in[6];
    const float* b2   = (const float*)d_in[7];
    const float* bng  = (const float*)d_in[8];
    const float* bnb  = (const float*)d_in[9];
    const float* bnm  = (const float*)d_in[10];
    const float* bnv  = (const float*)d_in[11];
    const float* pw   = (const float*)d_in[12];
    const float* pb   = (const float*)d_in[13];
    const float* fcw  = (const float*)d_in[14];
    const float* fcb  = (const float*)d_in[15];
    float* out = (float*)d_out;

    const size_t need = (size_t)3 * 12 * 8 * 2 * 1024;   // 589824 B of packed frags
    if (ws_size >= need) {
        unsigned short* wpk = (unsigned short*)d_ws;
        pack_w_frags<<<72, 256, 0, stream>>>(w1, w2, pw, wpk);
        fused_mfma<<<BB * NTB2, 256, 0, stream>>>(x, seq, w0, b0, b1, b2,
                                                  bng, bnb, bnm, bnv,
                                                  pb, fcw, fcb, wpk, out);
    } else {
        fused_pd<<<BB * NTB, 256, 0, stream>>>(x, seq, w0, b0, w1, b1, w2, b2,
                                               bng, bnb, bnm, bnv, pw, pb, fcw, fcb,
                                               out);
    }
}

// Round 6
// 111.203 us; speedup vs baseline: 4.5756x; 1.0353x over previous
//
#include <hip/hip_runtime.h>

#define BB   64
#define S    2048
#define HH   128
#define KCH  682
#define EPS  1e-5f

// ================= MFMA path =================
#define TT2   48          // output t per block (16 chunks)
#define NTB2  43          // ceil(2046/48)
#define NROWS 66          // h rows: t in [t0-3, t0+63)

typedef __attribute__((ext_vector_type(8))) short bf16x8;
typedef __attribute__((ext_vector_type(4))) short bf16x4v;
typedef __attribute__((ext_vector_type(4))) float f32x4;

__device__ __forceinline__ unsigned short bf16hi(float v) {
    return (unsigned short)(__float_as_uint(v) >> 16);   // truncation; lo captures residual
}
__device__ __forceinline__ float bf16f(unsigned short h) {
    return __uint_as_float(((unsigned)h) << 16);
}

// Pack W fragments in exact MFMA A-operand order (row=lane&15, k=(lane>>4)*8+j;
// any k-permutation error cancels against the B-read which uses the same mapping).
// Layout: frag_idx = ((mat*12+kb)*8+mc)*2+pl ; 512 ushort per frag (64 lanes x 8).
__global__ void pack_w_frags(const float* __restrict__ w1, const float* __restrict__ w2,
                             const float* __restrict__ pw, unsigned short* __restrict__ wpk) {
    int u = blockIdx.x * 256 + threadIdx.x;     // 18432 units
    if (u >= 18432) return;
    int lane = u & 63, mc = (u >> 6) & 7, kb = (u >> 9) % 12, mat = u / 6144;
    const float* src = (mat == 0) ? w1 : (mat == 1) ? w2 : pw;
    int c = mc * 16 + (lane & 15);
    int kbase = kb * 32 + ((lane >> 4) << 3);
    bf16x8 hv, lv;
    #pragma unroll
    for (int j = 0; j < 8; ++j) {
        int k = kbase + j, tap = k >> 7, ci = k & 127;   // K = tap*128 + ci
        float v = src[c * 384 + ci * 3 + tap];
        unsigned short h = bf16hi(v);
        float r = v - bf16f(h);
        hv[j] = (short)h;
        lv[j] = (short)bf16hi(r);
    }
    int fb = ((mat * 12 + kb) * 8 + mc) * 2;
    *(bf16x8*)(wpk + (size_t)(fb + 0) * 512 + lane * 8) = hv;
    *(bf16x8*)(wpk + (size_t)(fb + 1) * 512 + lane * 8) = lv;
}

// seq_lens may arrive as int64 (reference dtype) or int32. Detect (odd slots all-zero => int64).
__device__ __forceinline__ int read_seqlen(const int* seq, int b) {
    bool is64 = true;
    for (int i = 1; i < 64; i += 2) { if (seq[i] != 0) { is64 = false; break; } }
    return is64 ? seq[2 * b] : seq[b];
}

// swizzled byte address into a [NROWS][128] ushort plane: row rr, 16B-chunk index
__device__ __forceinline__ int haddr(int rr, int chunk) {
    return (rr << 8) | ((chunk ^ (rr & 15)) << 4);
}

// NT n-tiles of 16 t-positions; B rows = RBASE + tap + (lane&15) + nt*16
template<int NT, int RBASE>
__device__ __forceinline__ void conv_mfma_k(
        f32x4 (&acc)[2][NT], const unsigned short* __restrict__ wpk, int mat,
        const unsigned short* __restrict__ hHi, const unsigned short* __restrict__ hLo,
        int wv, int lane) {
    #pragma unroll
    for (int m = 0; m < 2; ++m)
        #pragma unroll
        for (int n = 0; n < NT; ++n) acc[m][n] = (f32x4){0.f, 0.f, 0.f, 0.f};

    const bf16x8* wp = (const bf16x8*)wpk;
    for (int kb = 0; kb < 12; ++kb) {
        const int fb = ((mat * 12 + kb) * 8 + wv * 2) * 2;   // this wave's 2 c-tiles
        bf16x8 a0h = wp[(size_t)(fb + 0) * 64 + lane];
        bf16x8 a0l = wp[(size_t)(fb + 1) * 64 + lane];
        bf16x8 a1h = wp[(size_t)(fb + 2) * 64 + lane];
        bf16x8 a1l = wp[(size_t)(fb + 3) * 64 + lane];
        const int tap = kb >> 2;
        const int chunk = (kb & 3) * 4 + (lane >> 4);
        const int rr0 = RBASE + tap + (lane & 15);
        __builtin_amdgcn_s_setprio(1);
        #pragma unroll
        for (int nt = 0; nt < NT; ++nt) {
            const int rr = rr0 + nt * 16;
            const int ad = haddr(rr, chunk);
            bf16x8 bh = *(const bf16x8*)((const char*)hHi + ad);
            bf16x8 bl = *(const bf16x8*)((const char*)hLo + ad);
            acc[0][nt] = __builtin_amdgcn_mfma_f32_16x16x32_bf16(a0h, bh, acc[0][nt], 0, 0, 0);
            acc[0][nt] = __builtin_amdgcn_mfma_f32_16x16x32_bf16(a0l, bh, acc[0][nt], 0, 0, 0);
            acc[0][nt] = __builtin_amdgcn_mfma_f32_16x16x32_bf16(a0h, bl, acc[0][nt], 0, 0, 0);
            acc[1][nt] = __builtin_amdgcn_mfma_f32_16x16x32_bf16(a1h, bh, acc[1][nt], 0, 0, 0);
            acc[1][nt] = __builtin_amdgcn_mfma_f32_16x16x32_bf16(a1l, bh, acc[1][nt], 0, 0, 0);
            acc[1][nt] = __builtin_amdgcn_mfma_f32_16x16x32_bf16(a1h, bl, acc[1][nt], 0, 0, 0);
        }
        __builtin_amdgcn_s_setprio(0);
    }
}

// BN+relu epilogue: output tt=nt*16+(lane&15), time t=t0+T_OFF+tt, row rr=tt+ROW_OFF
template<int NT, int ROW_OFF, int T_OFF>
__device__ __forceinline__ void conv_epilogue(
        f32x4 (&acc)[2][NT], const float* __restrict__ bias,
        const float* __restrict__ bng, const float* __restrict__ bnb,
        const float* __restrict__ bnm, const float* __restrict__ bnv, int layer,
        unsigned short* __restrict__ hHi, unsigned short* __restrict__ hLo,
        int wv, int lane, int t0) {
    #pragma unroll
    for (int m = 0; m < 2; ++m) {
        const int c0 = (wv * 2 + m) * 16 + (lane >> 4) * 4;
        const float4 bv = *(const float4*)&bias[c0];
        const float4 g  = *(const float4*)&bng[layer * 128 + c0];
        const float4 be = *(const float4*)&bnb[layer * 128 + c0];
        const float4 mn = *(const float4*)&bnm[layer * 128 + c0];
        const float4 vr = *(const float4*)&bnv[layer * 128 + c0];
        const float av[4] = { g.x * rsqrtf(vr.x + EPS), g.y * rsqrtf(vr.y + EPS),
                              g.z * rsqrtf(vr.z + EPS), g.w * rsqrtf(vr.w + EPS) };
        const float dv[4] = { be.x - mn.x * av[0], be.y - mn.y * av[1],
                              be.z - mn.z * av[2], be.w - mn.w * av[3] };
        const float bb[4] = { bv.x, bv.y, bv.z, bv.w };
        const int byte = c0 * 2, chunk = byte >> 4, off = byte & 15;
        #pragma unroll
        for (int nt = 0; nt < NT; ++nt) {
            const int tt = nt * 16 + (lane & 15);
            const int t = t0 + T_OFF + tt;
            const int rr = tt + ROW_OFF;
            const bool ok = (t >= 0) && (t < S);
            bf16x4v h4, l4;
            #pragma unroll
            for (int r = 0; r < 4; ++r) {
                float v = 0.f;
                if (ok) v = fmaf(fmaxf(acc[m][nt][r] + bb[r], 0.f), av[r], dv[r]);
                unsigned short h = bf16hi(v);
                float res = v - bf16f(h);
                h4[r] = (short)h;
                l4[r] = (short)bf16hi(res);
            }
            const int ad = haddr(rr, chunk) | off;
            *(bf16x4v*)((char*)hHi + ad) = h4;
            *(bf16x4v*)((char*)hLo + ad) = l4;
        }
    }
}

__global__ __launch_bounds__(256, 4)
void fused_mfma(const float* __restrict__ x, const int* __restrict__ seq,
                const float* __restrict__ w0, const float* __restrict__ b0,
                const float* __restrict__ b1, const float* __restrict__ b2,
                const float* __restrict__ bng, const float* __restrict__ bnb,
                const float* __restrict__ bnm, const float* __restrict__ bnv,
                const float* __restrict__ pb, const float* __restrict__ fcw,
                const float* __restrict__ fcb, const unsigned short* __restrict__ wpk,
                float* __restrict__ out) {
    __shared__ __align__(16) unsigned short hHi[NROWS * 128];   // 16896 B
    __shared__ __align__(16) unsigned short hLo[NROWS * 128];   // 16896 B
    __shared__ __align__(16) float xs[72];
    __shared__ float p0[6 * 128];
    __shared__ float zred[4][16];
    __shared__ int nch_s;

    const int tid = threadIdx.x;
    const int lane = tid & 63, wv = tid >> 6;
    const int b  = blockIdx.x / NTB2;
    const int jt = blockIdx.x - b * NTB2;
    const int t0 = jt * TT2;

    // ---- stage x (t0-4 .. t0+63) + conv0/bn0 per-channel constants ----
    if (tid < 68) {
        const int t = t0 - 4 + tid;
        xs[tid] = (t >= 0 && t < S) ? x[b * S + t] : 0.f;
    }
    if (tid < 128) {
        const int c = tid;
        p0[c]         = w0[c * 3 + 0];
        p0[128 + c]   = w0[c * 3 + 1];
        p0[2*128 + c] = w0[c * 3 + 2];
        p0[3*128 + c] = b0[c];
        const float a0 = bng[c] * rsqrtf(bnv[c] + EPS);
        p0[4*128 + c] = a0;
        p0[5*128 + c] = bnb[c] - bnm[c] * a0;
    }
    if (tid == 0) nch_s = read_seqlen(seq, b) / 3;
    __syncthreads();

    // ---- conv0 + bn0 -> h1 rows rr=0..65 (t = t0-3+rr), bf16 hi/lo ----
    for (int it = 0; it < 5; ++it) {
        const int u = tid + it * 256;              // 1056 units = 66 rows x 16 octets
        if (u < NROWS * 16) {
            const int rr = u >> 4, oct = u & 15, ci0 = oct * 8;
            const int t = t0 - 3 + rr;
            const bool ok = (t >= 0) && (t < S);
            const float xm = xs[rr], xc = xs[rr + 1], xp = xs[rr + 2];
            bf16x8 hv, lv;
            #pragma unroll
            for (int q = 0; q < 8; ++q) {
                const int c = ci0 + q;
                float v = 0.f;
                if (ok) {
                    float sa = fmaf(xp, p0[2*128 + c],
                               fmaf(xc, p0[128 + c],
                               fmaf(xm, p0[c], p0[3*128 + c])));
                    v = fmaf(fmaxf(sa, 0.f), p0[4*128 + c], p0[5*128 + c]);
                }
                unsigned short h = bf16hi(v);
                float res = v - bf16f(h);
                hv[q] = (short)h;
                lv[q] = (short)bf16hi(res);
            }
            const int ad = haddr(rr, oct);
            *(bf16x8*)((char*)hHi + ad) = hv;
            *(bf16x8*)((char*)hLo + ad) = lv;
        }
    }
    __syncthreads();

    // ---- conv1: B rows tap+l+nt*16 (0..65), outputs t=t0-2+tt -> rows tt+1 (1..64) ----
    {
        f32x4 acc1[2][4];
        conv_mfma_k<4, 0>(acc1, wpk, 0, hHi, hLo, wv, lane);
        __syncthreads();                            // all h1 reads done
        conv_epilogue<4, 1, -2>(acc1, b1, bng, bnb, bnm, bnv, 1, hHi, hLo, wv, lane, t0);
    }
    __syncthreads();

    // ---- conv2: B rows 2+tap+l+nt*16 (2..64), outputs t=t0+tt -> rows tt+3 (3..50) ----
    {
        f32x4 acc2[2][3];
        conv_mfma_k<3, 2>(acc2, wpk, 1, hHi, hLo, wv, lane);
        __syncthreads();                            // all h2 reads done
        conv_epilogue<3, 3, 0>(acc2, b2, bng, bnb, bnm, bnv, 2, hHi, hLo, wv, lane, t0);
    }
    __syncthreads();

    // ---- pre einsum: z[k][o], k = lane&15 (16 chunks), rows 3+3k+tap ----
    f32x4 pacc[2];
    pacc[0] = (f32x4){0.f, 0.f, 0.f, 0.f};
    pacc[1] = (f32x4){0.f, 0.f, 0.f, 0.f};
    {
        const bf16x8* wp = (const bf16x8*)wpk;
        const int klocal = lane & 15;
        for (int kb = 0; kb < 12; ++kb) {
            const int fb = ((2 * 12 + kb) * 8 + wv * 2) * 2;
            bf16x8 a0h = wp[(size_t)(fb + 0) * 64 + lane];
            bf16x8 a0l = wp[(size_t)(fb + 1) * 64 + lane];
            bf16x8 a1h = wp[(size_t)(fb + 2) * 64 + lane];
            bf16x8 a1l = wp[(size_t)(fb + 3) * 64 + lane];
            const int tap = kb >> 2;
            const int chunk = (kb & 3) * 4 + (lane >> 4);
            const int rr = 3 + 3 * klocal + tap;          // h3 row for t = t0+3k+tap
            const int ad = haddr(rr, chunk);
            bf16x8 bh = *(const bf16x8*)((const char*)hHi + ad);
            bf16x8 bl = *(const bf16x8*)((const char*)hLo + ad);
            __builtin_amdgcn_s_setprio(1);
            pacc[0] = __builtin_amdgcn_mfma_f32_16x16x32_bf16(a0h, bh, pacc[0], 0, 0, 0);
            pacc[0] = __builtin_amdgcn_mfma_f32_16x16x32_bf16(a0l, bh, pacc[0], 0, 0, 0);
            pacc[0] = __builtin_amdgcn_mfma_f32_16x16x32_bf16(a0h, bl, pacc[0], 0, 0, 0);
            pacc[1] = __builtin_amdgcn_mfma_f32_16x16x32_bf16(a1h, bh, pacc[1], 0, 0, 0);
            pacc[1] = __builtin_amdgcn_mfma_f32_16x16x32_bf16(a1l, bh, pacc[1], 0, 0, 0);
            pacc[1] = __builtin_amdgcn_mfma_f32_16x16x32_bf16(a1h, bl, pacc[1], 0, 0, 0);
            __builtin_amdgcn_s_setprio(0);
        }
    }

    // ---- relu(z+pb)*fcw, reduce over o ----
    float s0 = 0.f;
    #pragma unroll
    for (int m = 0; m < 2; ++m) {
        const int o0 = (wv * 2 + m) * 16 + (lane >> 4) * 4;
        const float4 pbv = *(const float4*)&pb[o0];
        const float4 fwv = *(const float4*)&fcw[o0];
        const float pbb[4] = { pbv.x, pbv.y, pbv.z, pbv.w };
        const float fww[4] = { fwv.x, fwv.y, fwv.z, fwv.w };
        #pragma unroll
        for (int r = 0; r < 4; ++r)
            s0 += fmaxf(pacc[m][r] + pbb[r], 0.f) * fww[r];
    }
    s0 += __shfl_xor(s0, 16);
    s0 += __shfl_xor(s0, 32);                      // sum over o within wave's 32 channels
    if (lane < 16) zred[wv][lane] = s0;            // k = lane
    __syncthreads();
    if (tid < 16) {
        const float zz = zred[0][tid] + zred[1][tid] + zred[2][tid] + zred[3][tid];
        const int kG = jt * 16 + tid;
        if (kG < KCH)
            out[b * KCH + kG] = (kG < nch_s) ? (zz + fcb[0]) : 0.f;
    }
}

// ================= fp32 fallback (round-3 verified) =================
#define TT   78
#define NTB  27
#define STRIDE 84

__device__ __forceinline__ void stage_w_fb(float* __restrict__ wtS,
                                           const float* __restrict__ wraw, int cc, int tid) {
    for (int i = tid; i < 6144; i += 256)
        wtS[i] = wraw[(i & 127) * 384 + cc * 3 + (i >> 7)];
}

__device__ __forceinline__ void conv_gemm_fb(float (&acc)[10][4],
                                             const float* __restrict__ wraw,
                                             const float* __restrict__ hAp,
                                             float* __restrict__ wtS,
                                             int tid, int c0, int tbase) {
    #pragma unroll
    for (int i = 0; i < 10; ++i)
        #pragma unroll
        for (int q = 0; q < 4; ++q) acc[i][q] = 0.f;
    for (int cc = 0; cc < HH; cc += 16) {
        __syncthreads();
        stage_w_fb(wtS, wraw, cc, tid);
        __syncthreads();
        for (int ci = 0; ci < 16; ++ci) {
            float hr[12];
            #pragma unroll
            for (int j = 0; j < 12; ++j) hr[j] = hAp[(cc + ci) * STRIDE + tbase + j];
            #pragma unroll
            for (int tap = 0; tap < 3; ++tap) {
                const float4 w = *(const float4*)&wtS[((ci * 3 + tap) << 7) + c0];
                #pragma unroll
                for (int i = 0; i < 10; ++i) {
                    const float h = hr[i + tap];
                    acc[i][0] = fmaf(h, w.x, acc[i][0]);
                    acc[i][1] = fmaf(h, w.y, acc[i][1]);
                    acc[i][2] = fmaf(h, w.z, acc[i][2]);
                    acc[i][3] = fmaf(h, w.w, acc[i][3]);
                }
            }
        }
    }
}

__global__ __launch_bounds__(256, 2)
void fused_pd(const float* __restrict__ x, const int* __restrict__ seq,
              const float* __restrict__ w0, const float* __restrict__ b0,
              const float* __restrict__ w1raw, const float* __restrict__ b1,
              const float* __restrict__ w2raw, const float* __restrict__ b2,
              const float* __restrict__ bng, const float* __restrict__ bnb,
              const float* __restrict__ bnm, const float* __restrict__ bnv,
              const float* __restrict__ pwraw, const float* __restrict__ pb,
              const float* __restrict__ fcw, const float* __restrict__ fcb,
              float* __restrict__ out) {
    __shared__ __align__(16) float hA[HH * STRIDE];
    __shared__ __align__(16) float wtS[6144];
    __shared__ __align__(16) float xsf[TT + 8];
    __shared__ int nch_s;

    const int tid = threadIdx.x;
    const int b  = blockIdx.x / NTB;
    const int jt = blockIdx.x - b * NTB;
    const int t0 = jt * TT;

    for (int j = tid; j < TT + 6; j += 256) {
        const int t = t0 - 3 + j;
        xsf[j] = (t >= 0 && t < S) ? x[b * S + t] : 0.f;
    }
    if (tid == 0) nch_s = read_seqlen(seq, b) / 3;

    const int cch = tid & 127;
    const float w0a = w0[cch * 3 + 0], w0b = w0[cch * 3 + 1], w0c = w0[cch * 3 + 2];
    const float bb0 = b0[cch];
    const float a0 = bng[cch] * rsqrtf(bnv[cch] + EPS);
    const float d0 = bnb[cch] - bnm[cch] * a0;
    __syncthreads();

    for (int i = tid; i < (TT + 4) * HH; i += 256) {
        const int ttl = i >> 7;
        const int t = t0 - 2 + ttl;
        float v = 0.f;
        if (t >= 0 && t < S) {
            float sa = fmaf(xsf[ttl + 2], w0c, fmaf(xsf[ttl + 1], w0b, fmaf(xsf[ttl], w0a, bb0)));
            v = fmaf(fmaxf(sa, 0.f), a0, d0);
        }
        hA[cch * STRIDE + ttl] = v;
    }

    const int cg = tid & 31, tg = tid >> 5;
    const int c0 = cg * 4;
    const int tbase = tg * 10;
    float acc[10][4];

    conv_gemm_fb(acc, w1raw, hA, wtS, tid, c0, tbase);
    {
        const float4 bv = *(const float4*)&b1[c0];
        const float4 g  = *(const float4*)&bng[HH + c0];
        const float4 be = *(const float4*)&bnb[HH + c0];
        const float4 mn = *(const float4*)&bnm[HH + c0];
        const float4 vr = *(const float4*)&bnv[HH + c0];
        float av[4] = { g.x * rsqrtf(vr.x + EPS), g.y * rsqrtf(vr.y + EPS),
                        g.z * rsqrtf(vr.z + EPS), g.w * rsqrtf(vr.w + EPS) };
        float dv[4] = { be.x - mn.x * av[0], be.y - mn.y * av[1],
                        be.z - mn.z * av[2], be.w - mn.w * av[3] };
        float bb[4] = { bv.x, bv.y, bv.z, bv.w };
        __syncthreads();
        #pragma unroll
        for (int i = 0; i < 10; ++i) {
            const int tt2 = tbase + i;
            const int t = t0 - 1 + tt2;
            const bool ok = (t >= 0) && (t < S);
            #pragma unroll
            for (int q = 0; q < 4; ++q) {
                float v = 0.f;
                if (ok) v = fmaf(fmaxf(acc[i][q] + bb[q], 0.f), av[q], dv[q]);
                hA[(c0 + q) * STRIDE + tt2] = v;
            }
        }
        __syncthreads();
    }

    conv_gemm_fb(acc, w2raw, hA, wtS, tid, c0, tbase);
    {
        const float4 bv = *(const float4*)&b2[c0];
        const float4 g  = *(const float4*)&bng[2 * HH + c0];
        const float4 be = *(const float4*)&bnb[2 * HH + c0];
        const float4 mn = *(const float4*)&bnm[2 * HH + c0];
        const float4 vr = *(const float4*)&bnv[2 * HH + c0];
        float av[4] = { g.x * rsqrtf(vr.x + EPS), g.y * rsqrtf(vr.y + EPS),
                        g.z * rsqrtf(vr.z + EPS), g.w * rsqrtf(vr.w + EPS) };
        float dv[4] = { be.x - mn.x * av[0], be.y - mn.y * av[1],
                        be.z - mn.z * av[2], be.w - mn.w * av[3] };
        float bb[4] = { bv.x, bv.y, bv.z, bv.w };
        __syncthreads();
        #pragma unroll
        for (int i = 0; i < 10; ++i) {
            const int tt3 = tbase + i;
            if (tt3 < TT) {
                const int t = t0 + tt3;
                #pragma unroll
                for (int q = 0; q < 4; ++q) {
                    float vv = 0.f;
                    if (t < S) vv = fmaf(fmaxf(acc[i][q] + bb[q], 0.f), av[q], dv[q]);
                    hA[(c0 + q) * STRIDE + tt3] = vv;
                }
            }
        }
        __syncthreads();
    }

    const int og = tid & 31, kg = tid >> 5;
    const int oo = og * 4;
    float pacc[4][4];
    #pragma unroll
    for (int j = 0; j < 4; ++j)
        #pragma unroll
        for (int q = 0; q < 4; ++q) pacc[j][q] = 0.f;

    for (int hc = 0; hc < HH; hc += 16) {
        __syncthreads();
        stage_w_fb(wtS, pwraw, hc, tid);
        __syncthreads();
        for (int h = 0; h < 16; ++h) {
            #pragma unroll
            for (int tap = 0; tap < 3; ++tap) {
                const float4 w = *(const float4*)&wtS[((h * 3 + tap) << 7) + oo];
                #pragma unroll
                for (int j = 0; j < 4; ++j) {
                    int kl = kg * 4 + j; kl = (kl > 25) ? 25 : kl;
                    const float hv = hA[(hc + h) * STRIDE + 3 * kl + tap];
                    pacc[j][0] = fmaf(hv, w.x, pacc[j][0]);
                    pacc[j][1] = fmaf(hv, w.y, pacc[j][1]);
                    pacc[j][2] = fmaf(hv, w.z, pacc[j][2]);
                    pacc[j][3] = fmaf(hv, w.w, pacc[j][3]);
                }
            }
        }
    }

    const float fcb0 = fcb[0];
    const float4 pbv = *(const float4*)&pb[oo];
    const float4 fwv = *(const float4*)&fcw[oo];
    const int nch = nch_s;
    #pragma unroll
    for (int j = 0; j < 4; ++j) {
        float s = fmaxf(pacc[j][0] + pbv.x, 0.f) * fwv.x
                + fmaxf(pacc[j][1] + pbv.y, 0.f) * fwv.y
                + fmaxf(pacc[j][2] + pbv.z, 0.f) * fwv.z
                + fmaxf(pacc[j][3] + pbv.w, 0.f) * fwv.w;
        #pragma unroll
        for (int m = 1; m < 32; m <<= 1) s += __shfl_xor(s, m, 64);
        if (og == 0) {
            const int kl = kg * 4 + j;
            const int kG = jt * 26 + kl;
            if (kl < 26 && kG < KCH)
                out[b * KCH + kG] = (kG < nch) ? (s + fcb0) : 0.f;
        }
    }
}

extern "C" void kernel_launch(void* const* d_in, const int* in_sizes, int n_in,
                              void* d_out, int out_size, void* d_ws, size_t ws_size,
                              hipStream_t stream) {
    (void)in_sizes; (void)n_in; (void)out_size;
    const float* x    = (const float*)d_in[0];
    const int*   seq  = (const int*)d_in[1];
    const float* w0   = (const float*)d_in[2];
    const float* b0   = (const float*)d_in[3];
    const float* w1   = (const float*)d_in[4];
    const float* b1   = (const float*)d_in[5];
    const float* w2   = (const float*)d_in[6];
    const float* b2   = (const float*)d_in[7];
    const float* bng  = (const float*)d_in[8];
    const float* bnb  = (const float*)d_in[9];
    const float* bnm  = (const float*)d_in[10];
    const float* bnv  = (const float*)d_in[11];
    const float* pw   = (const float*)d_in[12];
    const float* pb   = (const float*)d_in[13];
    const float* fcw  = (const float*)d_in[14];
    const float* fcb  = (const float*)d_in[15];
    float* out = (float*)d_out;

    const size_t need = (size_t)3 * 12 * 8 * 2 * 1024;   // 589824 B of packed frags
    if (ws_size >= need) {
        unsigned short* wpk = (unsigned short*)d_ws;
        pack_w_frags<<<72, 256, 0, stream>>>(w1, w2, pw, wpk);
        fused_mfma<<<BB * NTB2, 256, 0, stream>>>(x, seq, w0, b0, b1, b2,
                                                  bng, bnb, bnm, bnv,
                                                  pb, fcw, fcb, wpk, out);
    } else {
        fused_pd<<<BB * NTB, 256, 0, stream>>>(x, seq, w0, b0, w1, b1, w2, b2,
                                               bng, bnb, bnm, bnv, pw, pb, fcw, fcb,
                                               out);
    }
}